// Round 1
// baseline (977.060 us; speedup 1.0000x reference)
//
#include <hip/hip_runtime.h>

#define VOCAB 21
#define EMB 128
#define H1 64
#define G1 256   // 4*H1
#define H2 100
#define G2 400   // 4*H2
#define T1 500
#define TP 100
#define NB 1024

__device__ __forceinline__ float sigf(float x) { return 1.0f / (1.0f + __expf(-x)); }
__device__ __forceinline__ float tanh_fast(float x) { return 1.0f - 2.0f / (1.0f + __expf(2.0f * x)); }

// ---------------------------------------------------------------------------
// Kernel 0: proj_table[v][g] = dot(W_ih1[g,:], emb[v,:]) + b_ih1[g] + b_hh1[g]
// v==0 is the padding index (masked to zero input).
// ---------------------------------------------------------------------------
__global__ void k_table(const float* __restrict__ Wih, const float* __restrict__ emb,
                        const float* __restrict__ bih, const float* __restrict__ bhh,
                        float* __restrict__ table) {
    const int g = threadIdx.x;   // 0..255
    const int v = blockIdx.x;    // 0..20
    float s = bih[g] + bhh[g];
    if (v != 0) {
        const float* w = Wih + g * EMB;
        const float* e = emb + v * EMB;
        #pragma unroll 16
        for (int d = 0; d < EMB; ++d) s += w[d] * e[d];
    }
    table[v * G1 + g] = s;
}

// ---------------------------------------------------------------------------
// Kernel 1: layer-1 LSTM over T=500 + window-5 max pool. 2 batch rows/block.
// Thread g owns gate column g (W_hh1 row in 64 VGPRs). h, gates in LDS.
// ---------------------------------------------------------------------------
__global__ __launch_bounds__(256, 4) void k_lstm1(
    const int* __restrict__ xidx, const float* __restrict__ Whh,
    const float* __restrict__ table_g, float* __restrict__ x2) {
    __shared__ __align__(16) float table[VOCAB * G1];  // 21504 B
    __shared__ __align__(16) float hbuf[2 * H1];       // 512 B
    __shared__ __align__(16) float gates[2 * G1];      // 2048 B
    __shared__ int idxs[2 * T1];                       // 4000 B
    const int tid = threadIdx.x;
    const int b0 = blockIdx.x * 2;

    for (int i = tid; i < VOCAB * G1; i += 256) table[i] = table_g[i];
    for (int i = tid; i < 2 * T1; i += 256) {
        int r = i / T1, t = i - r * T1;
        idxs[i] = xidx[(b0 + r) * T1 + t];
    }
    if (tid < 2 * H1) hbuf[tid] = 0.0f;

    float w[H1];
    {
        const float4* w4 = reinterpret_cast<const float4*>(Whh + tid * H1);
        #pragma unroll
        for (int k = 0; k < 16; ++k) {
            float4 v = w4[k];
            w[4 * k + 0] = v.x; w[4 * k + 1] = v.y; w[4 * k + 2] = v.z; w[4 * k + 3] = v.w;
        }
    }

    float cc = 0.0f, pm = -1e30f;
    const int r_c = tid >> 6, j_c = tid & 63;  // combine mapping (tid < 128)

    for (int t = 0; t < T1; ++t) {
        __syncthreads();  // h ready
        const int i0 = idxs[t] * G1 + tid;
        const int i1 = idxs[T1 + t] * G1 + tid;
        float a0 = table[i0];
        float a1 = table[i1];
        const float4* h0 = reinterpret_cast<const float4*>(hbuf);
        const float4* h1 = reinterpret_cast<const float4*>(hbuf + H1);
        #pragma unroll
        for (int k = 0; k < 16; ++k) {
            float4 u = h0[k];
            float4 v = h1[k];
            a0 += w[4*k]*u.x + w[4*k+1]*u.y + w[4*k+2]*u.z + w[4*k+3]*u.w;
            a1 += w[4*k]*v.x + w[4*k+1]*v.y + w[4*k+2]*v.z + w[4*k+3]*v.w;
        }
        gates[tid] = a0;
        gates[G1 + tid] = a1;
        __syncthreads();  // gates ready; safe to overwrite h
        if (tid < 2 * H1) {
            const float* gr = gates + r_c * G1 + j_c;
            float gi = gr[0], gf = gr[H1], gg = gr[2 * H1], go = gr[3 * H1];
            cc = sigf(gf) * cc + sigf(gi) * tanh_fast(gg);
            float h = sigf(go) * tanh_fast(cc);
            hbuf[tid] = h;
            pm = fmaxf(pm, h);
            if ((t % 5) == 4) {
                x2[(b0 + r_c) * (TP * H1) + (t / 5) * H1 + j_c] = pm;
                pm = -1e30f;
            }
        }
    }
}

// ---------------------------------------------------------------------------
// Kernel 2: layer-2 LSTM over TP=100 + final FC+sigmoid. 4 batch rows/block.
// Thread g (<400) owns gate column g: W_ih2 row (64) + W_hh2 row (100) in VGPRs.
// Threads 400..511 double-buffer the next x2 tile during the gate phase.
// ---------------------------------------------------------------------------
__global__ __launch_bounds__(512, 2) void k_lstm2(
    const float* __restrict__ x2, const float* __restrict__ Wih,
    const float* __restrict__ Whh, const float* __restrict__ bih,
    const float* __restrict__ bhh, const float* __restrict__ fcw,
    const float* __restrict__ fcb, float* __restrict__ out) {
    __shared__ __align__(16) float h2[4 * 104];     // padded rows (416 B, 16-aligned)
    __shared__ __align__(16) float x2t[2][4 * 64];
    __shared__ __align__(16) float gates[4 * G2];
    const int tid = threadIdx.x;
    const int b0 = blockIdx.x * 4;

    float wih[64];
    float whh[100];
    float bsum = 0.0f;
    if (tid < G2) {
        const float4* p4 = reinterpret_cast<const float4*>(Wih + tid * 64);
        #pragma unroll
        for (int k = 0; k < 16; ++k) {
            float4 v = p4[k];
            wih[4 * k + 0] = v.x; wih[4 * k + 1] = v.y; wih[4 * k + 2] = v.z; wih[4 * k + 3] = v.w;
        }
        const float2* q2 = reinterpret_cast<const float2*>(Whh + tid * 100);
        #pragma unroll
        for (int k = 0; k < 50; ++k) {
            float2 v = q2[k];
            whh[2 * k + 0] = v.x; whh[2 * k + 1] = v.y;
        }
        bsum = bih[tid] + bhh[tid];
    }
    for (int i = tid; i < 4 * 104; i += 512) h2[i] = 0.0f;
    if (tid < 256) {  // tile 0
        int r = tid >> 6, k = tid & 63;
        x2t[0][tid] = x2[(b0 + r) * (TP * H1) + k];
    }

    float cc = 0.0f;
    const int r_c = (tid < G2) ? (tid / H2) : 0;
    const int j_c = (tid < G2) ? (tid % H2) : 0;
    int cur = 0;

    for (int tp = 0; tp < TP; ++tp) {
        __syncthreads();  // h2 + x2t[cur] ready
        if (tid < G2) {
            #pragma unroll
            for (int r = 0; r < 4; ++r) {
                float a = bsum;
                const float4* xr = reinterpret_cast<const float4*>(&x2t[cur][r * 64]);
                #pragma unroll
                for (int k = 0; k < 16; ++k) {
                    float4 u = xr[k];
                    a += wih[4*k]*u.x + wih[4*k+1]*u.y + wih[4*k+2]*u.z + wih[4*k+3]*u.w;
                }
                const float4* hr = reinterpret_cast<const float4*>(&h2[r * 104]);
                #pragma unroll
                for (int k = 0; k < 25; ++k) {
                    float4 u = hr[k];
                    a += whh[4*k]*u.x + whh[4*k+1]*u.y + whh[4*k+2]*u.z + whh[4*k+3]*u.w;
                }
                gates[r * G2 + tid] = a;
            }
        } else if (tp + 1 < TP) {
            for (int i = tid - G2; i < 256; i += 112) {
                int r = i >> 6, k = i & 63;
                x2t[cur ^ 1][i] = x2[(b0 + r) * (TP * H1) + (tp + 1) * H1 + k];
            }
        }
        __syncthreads();  // gates ready; safe to overwrite h2
        if (tid < G2) {
            float gi = gates[r_c * G2 + j_c];
            float gf = gates[r_c * G2 + j_c + H2];
            float gg = gates[r_c * G2 + j_c + 2 * H2];
            float go = gates[r_c * G2 + j_c + 3 * H2];
            cc = sigf(gf) * cc + sigf(gi) * tanh_fast(gg);
            float h = sigf(go) * tanh_fast(cc);
            h2[r_c * 104 + j_c] = h;
        }
        cur ^= 1;
    }
    __syncthreads();
    if (tid < 256) {  // FC + sigmoid: wave r reduces row r
        int r = tid >> 6, lane = tid & 63;
        float s = 0.0f;
        if (lane < H2) s += h2[r * 104 + lane] * fcw[lane];
        if (lane + 64 < H2) s += h2[r * 104 + lane + 64] * fcw[lane + 64];
        #pragma unroll
        for (int off = 32; off > 0; off >>= 1) s += __shfl_down(s, off);
        if (lane == 0) out[b0 + r] = sigf(s + fcb[0]);
    }
}

// ---------------------------------------------------------------------------
extern "C" void kernel_launch(void* const* d_in, const int* in_sizes, int n_in,
                              void* d_out, int out_size, void* d_ws, size_t ws_size,
                              hipStream_t stream) {
    const int*   x_idx = (const int*)  d_in[0];
    const float* emb   = (const float*)d_in[1];
    const float* Wih1  = (const float*)d_in[2];
    const float* Whh1  = (const float*)d_in[3];
    const float* bih1  = (const float*)d_in[4];
    const float* bhh1  = (const float*)d_in[5];
    const float* Wih2  = (const float*)d_in[6];
    const float* Whh2  = (const float*)d_in[7];
    const float* bih2  = (const float*)d_in[8];
    const float* bhh2  = (const float*)d_in[9];
    const float* fcw   = (const float*)d_in[10];
    const float* fcb   = (const float*)d_in[11];
    float* out = (float*)d_out;

    float* table = (float*)d_ws;                       // 21*256*4 = 21504 B
    float* x2    = (float*)((char*)d_ws + 32768);      // B*100*64*4 = 26.2 MB

    k_table<<<VOCAB, G1, 0, stream>>>(Wih1, emb, bih1, bhh1, table);
    k_lstm1<<<NB / 2, 256, 0, stream>>>(x_idx, Whh1, table, x2);
    k_lstm2<<<NB / 4, 512, 0, stream>>>(x2, Wih2, Whh2, bih2, bhh2, fcw, fcb, out);
}

// Round 2
// 369.728 us; speedup vs baseline: 2.6426x; 2.6426x over previous
//
#include <hip/hip_runtime.h>

#define VOCAB 21
#define EMB 128
#define H1 64
#define G1 256
#define H2 100
#define G2 400
#define T1 500
#define TP 100
#define NB 1024
#define TBL_LD 260   // padded table row stride (f32): (260*v+4c) spreads banks

typedef __attribute__((ext_vector_type(8))) short bf16x8;
typedef __attribute__((ext_vector_type(4))) float f32x4;

__device__ __forceinline__ float sigf(float x){ return 1.0f/(1.0f+__expf(-x)); }
__device__ __forceinline__ float tanhf_(float x){ return 1.0f - 2.0f/(1.0f+__expf(2.0f*x)); }
__device__ __forceinline__ short f2bf(float x){
    union { float f; unsigned u; } v; v.f = x;
    unsigned r = (v.u + 0x7FFFu + ((v.u >> 16) & 1u)) >> 16;   // RNE
    return (short)r;
}

// ---------------------------------------------------------------------------
// Kernel 0: permuted xproj table. table[v][4*cell+gate] =
//   dot(W_ih1[gate*64+cell,:], emb[v,:]) + b_ih1[..] + b_hh1[..]   (v==0 -> bias only)
// ---------------------------------------------------------------------------
__global__ void k_table(const float* __restrict__ Wih, const float* __restrict__ emb,
                        const float* __restrict__ bih, const float* __restrict__ bhh,
                        float* __restrict__ table){
    const int p = threadIdx.x;           // permuted gate-col 0..255
    const int v = blockIdx.x;
    const int orig = (p & 3) * H1 + (p >> 2);
    float s = bih[orig] + bhh[orig];
    if (v != 0){
        const float* w = Wih + orig * EMB;
        const float* e = emb + v * EMB;
        #pragma unroll 16
        for (int d = 0; d < EMB; ++d) s += w[d]*e[d];
    }
    table[v*TBL_LD + p] = s;
}

// ---------------------------------------------------------------------------
// Kernel 1: layer-1 LSTM, MFMA recurrence. 4 batch rows/block, 256 blocks.
// gates^T = Whh' (bf16, A-frags in regs) x h^T (bf16, LDS). Cell update is
// lane-local: acc regs 0..3 = (i,f,g,o) of one (cell,row). Max-pool window 5.
// ---------------------------------------------------------------------------
__global__ __launch_bounds__(256, 2) void k_lstm1(
    const int* __restrict__ xidx, const float* __restrict__ Whh,
    const float* __restrict__ tbl_g, float* __restrict__ x2){
  __shared__ __align__(16) float table[VOCAB*TBL_LD];        // 21840 B
  __shared__ __align__(16) unsigned short hlds[16*64];       // 2048 B, XOR-swizzled
  __shared__ __align__(16) float glds[4*16*4*4];             // 4 KB: [wave][jj][r][gate]
  __shared__ int idxs[4*T1];                                 // 8000 B

  const int tid = threadIdx.x;
  const int w = tid >> 6, l = tid & 63;
  const int b0 = blockIdx.x * 4;

  for (int i = tid; i < VOCAB*TBL_LD; i += 256) table[i] = tbl_g[i];
  for (int i = tid; i < 4*T1; i += 256){
      int r = i / T1, t = i - r*T1;
      idxs[i] = xidx[(b0 + r)*T1 + t];
  }
  for (int i = tid; i < 16*64; i += 256) hlds[i] = 0;        // rows 4..15 stay 0

  // A fragments (permuted Whh, bf16), persistent: afrag[tile][kchunk]
  bf16x8 afrag[4][2];
  {
      const int m = l & 15, kg = l >> 4;
      #pragma unroll
      for (int tt = 0; tt < 4; ++tt){
          const int p = 16*(4*w + tt) + m;
          const int orig = (p & 3) * H1 + (p >> 2);
          #pragma unroll
          for (int c = 0; c < 2; ++c){
              const float* src = Whh + orig*H1 + c*32 + kg*8;
              bf16x8 f;
              #pragma unroll
              for (int j = 0; j < 8; ++j) f[j] = f2bf(src[j]);
              afrag[tt][c] = f;
          }
      }
  }

  // cell-phase constants: lane l handles (row = l&3, cell = 16w + (l>>2))
  const int r_c = l & 3;
  const int cellG = 16*w + (l >> 2);
  char* gbase = (char*)glds;
  char* hbase = (char*)hlds;
  const int gbyte   = w*1024 + l*16;
  const int hw_byte = (r_c*128 + 2*cellG) ^ ((r_c & 7) << 4);
  const int m = l & 15, kg = l >> 4;
  const int rb0 = (m*128 + 2*(kg*8))      ^ ((m & 7) << 4);
  const int rb1 = (m*128 + 2*(32 + kg*8)) ^ ((m & 7) << 4);

  float cc = 0.f, pm = -1e30f;
  __syncthreads();

  for (int t = 0; t < T1; ++t){
      // phase 1: MFMA (hlds holds h(t-1), bf16)
      bf16x8 bf0 = *(const bf16x8*)(hbase + rb0);
      bf16x8 bf1 = *(const bf16x8*)(hbase + rb1);
      f32x4 acc[4];
      #pragma unroll
      for (int tt = 0; tt < 4; ++tt){
          f32x4 z = {0.f,0.f,0.f,0.f};
          z = __builtin_amdgcn_mfma_f32_16x16x32_bf16(afrag[tt][0], bf0, z, 0,0,0);
          z = __builtin_amdgcn_mfma_f32_16x16x32_bf16(afrag[tt][1], bf1, z, 0,0,0);
          acc[tt] = z;
      }
      // wave-local gate shuffle: 16 producer lanes -> 64 consumer lanes
      if ((l & 15) < 4){
          #pragma unroll
          for (int tt = 0; tt < 4; ++tt){
              int jj = 4*tt + (l >> 4);
              *(f32x4*)(gbase + w*1024 + jj*64 + (l & 15)*16) = acc[tt];
          }
      }
      asm volatile("s_waitcnt lgkmcnt(0)" ::: "memory");
      f32x4 gv = *(const f32x4*)(gbase + gbyte);
      f32x4 tv = *(const f32x4*)(&table[idxs[r_c*T1 + t]*TBL_LD + 4*cellG]);
      float gi = gv[0] + tv[0];
      float gf = gv[1] + tv[1];
      float gg = gv[2] + tv[2];
      float go = gv[3] + tv[3];
      __syncthreads();   // all waves finished reading hlds
      cc = sigf(gf)*cc + sigf(gi)*tanhf_(gg);
      float h = sigf(go)*tanhf_(cc);
      *(unsigned short*)(hbase + hw_byte) = (unsigned short)f2bf(h);
      pm = fmaxf(pm, h);
      if ((t % 5) == 4){
          x2[(b0 + r_c)*(TP*H1) + (t/5)*H1 + cellG] = pm;
          pm = -1e30f;
      }
      __syncthreads();   // publish h(t) before next MFMA reads
  }
}

// ---------------------------------------------------------------------------
// Kernel 2: layer-2 LSTM, MFMA, B = [x(64) | h(100, pad 128)] bf16 in LDS.
// 4 rows/block, 256 blocks, 8 waves; 25 gate tiles split 4,3,3,... per wave.
// ---------------------------------------------------------------------------
__global__ __launch_bounds__(512, 2) void k_lstm2(
    const float* __restrict__ x2, const float* __restrict__ Wih,
    const float* __restrict__ Whh, const float* __restrict__ bih,
    const float* __restrict__ bhh, const float* __restrict__ fcw,
    const float* __restrict__ fcb, float* __restrict__ out){
  __shared__ __align__(16) unsigned short blds[16*192];   // 6144 B, swizzled
  __shared__ __align__(16) float glds[8*16*4*4];          // 8 KB
  __shared__ float fcred[8][4];

  const int tid = threadIdx.x;
  const int w = tid >> 6, l = tid & 63;
  const int b0 = blockIdx.x * 4;
  const int tlo = (w == 0) ? 0 : 3*w + 1;
  const int nt  = (w == 0) ? 4 : 3;

  for (int i = tid; i < 16*192; i += 512) blds[i] = 0;    // rows 4..15 & k-pad stay 0

  // A-fragments: permuted [W_ih2 | W_hh2], bf16, persistent
  bf16x8 afrag[4][6];
  {
      const int m = l & 15, kg = l >> 4;
      #pragma unroll
      for (int tt = 0; tt < 4; ++tt){
          if (tt < nt){
              const int p = 16*(tlo + tt) + m;
              const int cell = p >> 2, gate = p & 3;
              #pragma unroll
              for (int c = 0; c < 6; ++c){
                  bf16x8 f;
                  #pragma unroll
                  for (int j = 0; j < 8; ++j){
                      int k = c*32 + kg*8 + j;
                      float v = 0.f;
                      if (k < 64)            v = Wih[(gate*H2 + cell)*H1 + k];
                      else if (k < 64 + H2)  v = Whh[(gate*H2 + cell)*H2 + (k - 64)];
                      f[j] = f2bf(v);
                  }
                  afrag[tt][c] = f;
              }
          }
      }
  }

  const int r_c = l & 3;
  const int cl  = l >> 2;
  const bool act = cl < 4*nt;
  const int cellG = min(4*tlo + cl, H2 - 1);
  f32x4 bias;
  #pragma unroll
  for (int g = 0; g < 4; ++g) bias[g] = bih[g*H2 + cellG] + bhh[g*H2 + cellG];
  const float fw = fcw[cellG];

  char* bbase = (char*)blds;
  char* gbase = (char*)glds;
  const int m = l & 15, kg = l >> 4;
  int rb[6];
  #pragma unroll
  for (int c = 0; c < 6; ++c)
      rb[c] = (m*384 + 2*(c*32 + kg*8)) ^ ((m & 7) << 4);
  const int hw_byte = (r_c*384 + 2*(64 + cellG)) ^ ((r_c & 7) << 4);
  const int xr = tid >> 6, xk = tid & 63;                    // x-staging role (tid<256)
  const int xw_byte = (xr*384 + 2*xk) ^ ((xr & 7) << 4);

  if (tid < 256){  // preload x(0)
      float v = x2[(b0 + xr)*(TP*H1) + xk];
      *(unsigned short*)(bbase + xw_byte) = (unsigned short)f2bf(v);
  }
  float cc = 0.f, h = 0.f;
  __syncthreads();

  for (int t = 0; t < TP; ++t){
      float xnext = 0.f;
      if (tid < 256 && t + 1 < TP)                           // T14: issue early
          xnext = x2[(b0 + xr)*(TP*H1) + (t+1)*H1 + xk];
      bf16x8 bf[6];
      #pragma unroll
      for (int c = 0; c < 6; ++c) bf[c] = *(const bf16x8*)(bbase + rb[c]);
      f32x4 acc[4];
      #pragma unroll
      for (int tt = 0; tt < 4; ++tt){
          if (tt < nt){
              f32x4 z = {0.f,0.f,0.f,0.f};
              #pragma unroll
              for (int c = 0; c < 6; ++c)
                  z = __builtin_amdgcn_mfma_f32_16x16x32_bf16(afrag[tt][c], bf[c], z, 0,0,0);
              acc[tt] = z;
          }
      }
      if ((l & 15) < 4){
          #pragma unroll
          for (int tt = 0; tt < 4; ++tt){
              if (tt < nt){
                  int jj = 4*tt + (l >> 4);
                  *(f32x4*)(gbase + w*1024 + jj*64 + (l & 15)*16) = acc[tt];
              }
          }
      }
      asm volatile("s_waitcnt lgkmcnt(0)" ::: "memory");
      f32x4 gv = *(const f32x4*)(gbase + w*1024 + l*16);
      __syncthreads();   // all B-frag reads done; safe to overwrite blds
      if (act){
          float gi = gv[0] + bias[0];
          float gf = gv[1] + bias[1];
          float gg = gv[2] + bias[2];
          float go = gv[3] + bias[3];
          cc = sigf(gf)*cc + sigf(gi)*tanhf_(gg);
          h = sigf(go)*tanhf_(cc);
          *(unsigned short*)(bbase + hw_byte) = (unsigned short)f2bf(h);
      }
      if (tid < 256 && t + 1 < TP)                           // write-late
          *(unsigned short*)(bbase + xw_byte) = (unsigned short)f2bf(xnext);
      __syncthreads();
  }

  // FC + sigmoid: reduce over cells (lanes with same l&3), then across waves
  float p = act ? h * fw : 0.f;
  p += __shfl_xor(p, 4);
  p += __shfl_xor(p, 8);
  p += __shfl_xor(p, 16);
  p += __shfl_xor(p, 32);
  if (l < 4) fcred[w][l] = p;
  __syncthreads();
  if (tid < 4){
      float s = 0.f;
      #pragma unroll
      for (int ww = 0; ww < 8; ++ww) s += fcred[ww][tid];
      out[b0 + tid] = sigf(s + fcb[0]);
  }
}

// ---------------------------------------------------------------------------
extern "C" void kernel_launch(void* const* d_in, const int* in_sizes, int n_in,
                              void* d_out, int out_size, void* d_ws, size_t ws_size,
                              hipStream_t stream) {
    const int*   x_idx = (const int*)  d_in[0];
    const float* emb   = (const float*)d_in[1];
    const float* Wih1  = (const float*)d_in[2];
    const float* Whh1  = (const float*)d_in[3];
    const float* bih1  = (const float*)d_in[4];
    const float* bhh1  = (const float*)d_in[5];
    const float* Wih2  = (const float*)d_in[6];
    const float* Whh2  = (const float*)d_in[7];
    const float* bih2  = (const float*)d_in[8];
    const float* bhh2  = (const float*)d_in[9];
    const float* fcw   = (const float*)d_in[10];
    const float* fcb   = (const float*)d_in[11];
    float* out = (float*)d_out;

    float* table = (float*)d_ws;                       // 21*260*4 = 21840 B
    float* x2    = (float*)((char*)d_ws + 32768);      // 1024*100*64*4 = 26.2 MB

    k_table<<<VOCAB, G1, 0, stream>>>(Wih1, emb, bih1, bhh1, table);
    k_lstm1<<<NB / 4, 256, 0, stream>>>(x_idx, Whh1, table, x2);
    k_lstm2<<<NB / 4, 512, 0, stream>>>(x2, Wih2, Whh2, bih2, bhh2, fcw, fcb, out);
}